// Round 8
// baseline (2069.950 us; speedup 1.0000x reference)
//
#include <hip/hip_runtime.h>

// Neural-ODE RK4, swapped-operand MFMA: z^T = W^T @ h^T.
// ALLOCATOR LAW (R4-R7 measured): arch-VGPR budget = 1024/waves_per_WG;
// amdgpu_waves_per_eu is ignored. -> 4-wave (256-thr) blocks get 256 regs.
// 64 blocks x 16 batch rows (full M=16 frags, no broadcast waste);
// 4 waves x 64 hidden cols. Weight homes: L0 in LDS (128KB); L1 in regs
// (wreg[4][8] = 128 VGPRs); L2+L3 STREAMED from L2$ per eval out of a
// pre-packed frag buffer (pack_kernel), double-buffered 4-frag chunks
// (32 regs in flight), chunk 0 prefetched a full layer ahead.
// At 64 blocks each CU gets ~224 B/cy of L2 BW -> 32KB/wave/layer in ~585cy,
// hidden under MFMA+LDS. h-tile [16][256] fp16 (8KB x2), swizzle
// byte ^= (row&7)<<4 -> 2-way-max ds_read_b128. RK4 state fp32 in regs.

#define T_ 128
#define IN_ 32
#define H_ 256

typedef _Float16 half8 __attribute__((ext_vector_type(8)));
typedef _Float16 half4 __attribute__((ext_vector_type(4)));
typedef float f32x4 __attribute__((ext_vector_type(4)));

__device__ __forceinline__ f32x4 mfma16(half8 a, half8 b, f32x4 c) {
    return __builtin_amdgcn_mfma_f32_16x16x32_f16(a, b, c, 0, 0, 0);
}

__device__ __forceinline__ half4 cvt4(f32x4 v) {
    half4 h;
    h[0] = (_Float16)v[0]; h[1] = (_Float16)v[1];
    h[2] = (_Float16)v[2]; h[3] = (_Float16)v[3];
    return h;
}

__device__ __forceinline__ f32x4 lips4(f32x4 v) {
    f32x4 r;
#pragma unroll
    for (int e = 0; e < 4; ++e) {
        float x = v[e];
        r[e] = 0.909f * x * __builtin_amdgcn_rcpf(1.f + __expf(-x));
    }
    return r;
}

// ---- h-tile read: lane (lr,lk) reads row lr, colbyte ks*64+lk*16, phys
// colbyte ^= (lr&7)<<4.  pe/po keep every read base + compile-time imm.
#define RDH(KS, BUF) (*(const half8*)(ht + (BUF) + (((KS) & 1) ? (po + ((KS)-1)*64) : (pe + (KS)*64))))
#define RDA(C, KS)   (*(const half8*)(w0b + (C)*8192 + (KS)*1024))

#define LOADB(BUF) do { b0=RDH(0,BUF); b1=RDH(1,BUF); b2=RDH(2,BUF); b3=RDH(3,BUF); \
                        b4=RDH(4,BUF); b5=RDH(5,BUF); b6=RDH(6,BUF); b7=RDH(7,BUF); } while (0)

#define L0_KS(KS, BK) do { \
    half8 a0_=RDA(0,KS), a1_=RDA(1,KS), a2_=RDA(2,KS), a3_=RDA(3,KS); \
    acc0=mfma16(a0_,BK,acc0); acc1=mfma16(a1_,BK,acc1); \
    acc2=mfma16(a2_,BK,acc2); acc3=mfma16(a3_,BK,acc3); } while (0)
#define LAYER_L0 do { L0_KS(0,b0); L0_KS(1,b1); L0_KS(2,b2); L0_KS(3,b3); \
                      L0_KS(4,b4); L0_KS(5,b5); L0_KS(6,b6); L0_KS(7,b7); } while (0)

#define REG_KS(KS, BK) do { \
    acc0=mfma16(wreg[0][KS],BK,acc0); acc1=mfma16(wreg[1][KS],BK,acc1); \
    acc2=mfma16(wreg[2][KS],BK,acc2); acc3=mfma16(wreg[3][KS],BK,acc3); } while (0)
#define LAYER_REG do { REG_KS(0,b0); REG_KS(1,b1); REG_KS(2,b2); REG_KS(3,b3); \
                       REG_KS(4,b4); REG_KS(5,b5); REG_KS(6,b6); REG_KS(7,b7); } while (0)

// ---- streamed layers: frag f = c*8+ks at wpb + f*1024 (per-lane base incl l*16)
#define LD4(D0,D1,D2,D3,P,F) do { \
    D0=*(const half8*)((P)+((F)+0)*1024); D1=*(const half8*)((P)+((F)+1)*1024); \
    D2=*(const half8*)((P)+((F)+2)*1024); D3=*(const half8*)((P)+((F)+3)*1024); } while (0)

#define MA4(ACC) do { ACC=mfma16(sa0,b0,ACC); ACC=mfma16(sa1,b1,ACC); \
                      ACC=mfma16(sa2,b2,ACC); ACC=mfma16(sa3,b3,ACC); } while (0)
#define MB4(ACC) do { ACC=mfma16(sb0,b4,ACC); ACC=mfma16(sb1,b5,ACC); \
                      ACC=mfma16(sb2,b6,ACC); ACC=mfma16(sb3,b7,ACC); } while (0)

// entry condition: sa holds frags (c=0, ks0-3) of this layer (prefetched).
// exit: sa holds frags 0-3 of PN (next stream layer / next eval's L2).
#define STREAM_LAYER(WP, PN) do { \
    LD4(sb0,sb1,sb2,sb3, WP, 4);   MA4(acc0); \
    LD4(sa0,sa1,sa2,sa3, WP, 8);   MB4(acc0); \
    LD4(sb0,sb1,sb2,sb3, WP, 12);  MA4(acc1); \
    LD4(sa0,sa1,sa2,sa3, WP, 16);  MB4(acc1); \
    LD4(sb0,sb1,sb2,sb3, WP, 20);  MA4(acc2); \
    LD4(sa0,sa1,sa2,sa3, WP, 24);  MB4(acc2); \
    LD4(sb0,sb1,sb2,sb3, WP, 28);  MA4(acc3); \
    LD4(sa0,sa1,sa2,sa3, PN, 0);   MB4(acc3); } while (0)

#define ACC_INIT(LY) do { \
    acc0 = *(const f32x4*)(bias4 + (LY)*H_ +  0); \
    acc1 = *(const f32x4*)(bias4 + (LY)*H_ + 16); \
    acc2 = *(const f32x4*)(bias4 + (LY)*H_ + 32); \
    acc3 = *(const f32x4*)(bias4 + (LY)*H_ + 48); } while (0)

#define ACT_STORE(BUF) do { \
    *(half4*)(ht + (BUF) + wo0)        = cvt4(lips4(acc0)); \
    *(half4*)(ht + (BUF) + (wo0^32))   = cvt4(lips4(acc1)); \
    *(half4*)(ht + (BUF) + (wo0^64))   = cvt4(lips4(acc2)); \
    *(half4*)(ht + (BUF) + (wo0^96))   = cvt4(lips4(acc3)); } while (0)

#define STORE_Y(BUF, V0, V1, V2, V3) do { \
    *(half4*)(ht + (BUF) + wo0)        = cvt4(V0); \
    *(half4*)(ht + (BUF) + (wo0^32))   = cvt4(V1); \
    *(half4*)(ht + (BUF) + (wo0^64))   = cvt4(V2); \
    *(half4*)(ht + (BUF) + (wo0^96))   = cvt4(V3); } while (0)

// pack Wf[2],Wf[3] into per-lane-contiguous A-frags:
// byte = (ly*4+w)*32768 + (c*8+ks)*1024 + lane*16
__global__ __launch_bounds__(256)
void pack_kernel(const float* __restrict__ Wf, _Float16* __restrict__ wpack)
{
    int idx = blockIdx.x * 256 + threadIdx.x;        // 0..16383
    int lane = idx & 63, ks = (idx >> 6) & 7, c = (idx >> 9) & 3;
    int w = (idx >> 11) & 3, ly = (idx >> 13) & 1;
    int col = w*64 + c*16 + (lane & 15);
    int row = ks*32 + (lane >> 4) * 8;
    const float* src = Wf + ((size_t)(ly + 2) * H_ + row) * H_ + col;
    half8 v;
#pragma unroll
    for (int j = 0; j < 8; ++j) v[j] = (_Float16)src[(size_t)j * H_];
    *(half8*)(wpack + (size_t)idx * 8) = v;
}

__global__ __attribute__((amdgpu_flat_work_group_size(256, 256), amdgpu_waves_per_eu(1, 1)))
void ncde_kernel(const float* __restrict__ coeffs,
                 const float* __restrict__ times,
                 const float* __restrict__ W_init,
                 const float* __restrict__ b_init,
                 const float* __restrict__ Wf,
                 const float* __restrict__ bfv,
                 const _Float16* __restrict__ wpack,
                 _Float16* __restrict__ ybuf)
{
    extern __shared__ char smem[];
    _Float16* w0   = (_Float16*)smem;                      // 128 KiB [ct16][ks8][ln64][8]
    char*     ht   = smem + 131072;                        // 2 x 8 KiB swizzled [16][256] f16
    float*    bias = (float*)(smem + 131072 + 16384);      // [4][256] f32
    float*    tlds = (float*)(smem + 131072 + 16384 + 4096); // [128] f32

    const int tid = threadIdx.x;        // 0..255
    const int l   = tid & 63;
    const int w   = tid >> 6;           // wave 0..3, owns cols [w*64, w*64+64)
    const int lr  = l & 15;             // batch row
    const int lk  = l >> 4;             // 0..3
    const int bc  = blockIdx.x;         // 0..63, rows bc*16..bc*16+15

    const int swz  = (lr & 7) << 4;
    const int base = lr*512 + ((lk*16) ^ (swz & 0x30));
    const int sswz = swz & 0x40;
    const int pe   = base + sswz;
    const int po   = base + 64 - sswz;
    const int wo0  = lr*512 + (((w*128) | (lk*8)) ^ swz);
    const char*  w0b   = (const char*)w0 + (size_t)w * 32768 + l * 16;
    const float* bias4 = bias + w*64 + lk*4;
    const char*  wpb2  = (const char*)wpack + (size_t)(0*4 + w) * 32768 + l * 16;
    const char*  wpb3  = (const char*)wpack + (size_t)(1*4 + w) * 32768 + l * 16;

    // ---------------- prologue ----------------
    for (int i = tid; i < 4 * H_; i += 256) bias[i] = bfv[i];
    if (tid < T_) tlds[tid] = times[tid];

    // layer-0 W^T A-frags: entry e=(ct*8+ks)*64+ln
    for (int e = tid; e < 8192; e += 256) {
        int ct = e >> 9, ks = (e >> 6) & 7, ln = e & 63;
        const float* src = Wf + (size_t)(ks*32 + ((ln >> 4) << 3)) * H_ + ct*16 + (ln & 15);
        half8 v;
#pragma unroll
        for (int j = 0; j < 8; ++j) v[j] = (_Float16)src[(size_t)j * H_];
        *(half8*)(w0 + (size_t)e * 8) = v;
    }

    // layer-1 W^T A-frags in regs (128 VGPRs): this wave's 64 cols
    half8 wreg[4][8];
#pragma unroll
    for (int c = 0; c < 4; ++c)
#pragma unroll
        for (int ks = 0; ks < 8; ++ks) {
            const float* src = Wf + ((size_t)H_ + ks*32 + lk*8) * H_ + w*64 + c*16 + lr;
            half8 v;
#pragma unroll
            for (int j = 0; j < 8; ++j) v[j] = (_Float16)src[(size_t)j * H_];
            wreg[c][ks] = v;
        }

    // y0 = coeffs[:,0,:] @ W_init + b_init  (fp32 VALU, one-time)
    // lane holds y[bc*16+lr][w*64 + c*16 + lk*4 + r]
    f32x4 y0v, y1v, y2v, y3v;
    {
        const float* crow = coeffs + (size_t)(bc*16 + lr) * (T_ * IN_);
#pragma unroll
        for (int c = 0; c < 4; ++c) {
            f32x4 acc;
#pragma unroll
            for (int r = 0; r < 4; ++r) {
                int col = w*64 + c*16 + lk*4 + r;
                float s = b_init[col];
                for (int k = 0; k < IN_; ++k)
                    s += crow[k] * W_init[(size_t)k * H_ + col];
                acc[r] = s;
            }
            if (c == 0) y0v = acc; else if (c == 1) y1v = acc;
            else if (c == 2) y2v = acc; else y3v = acc;
        }
    }

    STORE_Y(0, y0v, y1v, y2v, y3v);
    __syncthreads();
    {   // dump t=0: unswizzle -> linear [16][256] f16, coalesced 32B/thread
        int drow = tid >> 4, dcb = (tid & 15) * 32, dsw = (drow & 7) << 4;
        const char* sp = ht + drow * 512;
        uint4 a = *(const uint4*)(sp + (dcb ^ dsw));
        uint4 bq = *(const uint4*)(sp + ((dcb + 16) ^ dsw));
        char* dst = (char*)ybuf + (size_t)(bc * T_) * 8192 + tid * 32;
        *(uint4*)dst = a; *(uint4*)(dst + 16) = bq;
    }

    half8 b0, b1, b2, b3, b4, b5, b6, b7;
    half8 sa0, sa1, sa2, sa3, sb0, sb1, sb2, sb3;
    LD4(sa0, sa1, sa2, sa3, wpb2, 0);     // prefetch L2-layer chunk 0 (eval 0)

#pragma unroll 1
    for (int st = 0; st < T_ - 1; ++st) {
        float dt = tlds[st + 1] - tlds[st];
        f32x4 ks0v, ks1v, ks2v, ks3v;
#pragma unroll 1
        for (int s = 0; s < 4; ++s) {
            f32x4 acc0, acc1, acc2, acc3;
            ACC_INIT(0); LOADB(0);    LAYER_L0;             ACT_STORE(8192); __syncthreads();
            ACC_INIT(1); LOADB(8192); LAYER_REG;            ACT_STORE(0);    __syncthreads();
            ACC_INIT(2); LOADB(0);    STREAM_LAYER(wpb2, wpb3); ACT_STORE(8192); __syncthreads();
            ACC_INIT(3); LOADB(8192); STREAM_LAYER(wpb3, wpb2);   // k = acc (bias folded);
                                                                  // exit: sa = next eval's L2 chunk0
            if (s == 0)      { ks0v = acc0;       ks1v = acc1;       ks2v = acc2;       ks3v = acc3; }
            else if (s < 3)  { ks0v += 2.f*acc0;  ks1v += 2.f*acc1;  ks2v += 2.f*acc2;  ks3v += 2.f*acc3; }
            else             { ks0v += acc0;      ks1v += acc1;      ks2v += acc2;      ks3v += acc3; }
            if (s < 3) {
                float cy = (s == 2) ? dt : 0.5f * dt;
                STORE_Y(0, y0v + cy*acc0, y1v + cy*acc1, y2v + cy*acc2, y3v + cy*acc3);
            } else {
                float c6 = dt * (1.f / 6.f);
                y0v += c6*ks0v; y1v += c6*ks1v; y2v += c6*ks2v; y3v += c6*ks3v;
                STORE_Y(0, y0v, y1v, y2v, y3v);
            }
            __syncthreads();
        }
        {   // dump y at t = st+1
            int drow = tid >> 4, dcb = (tid & 15) * 32, dsw = (drow & 7) << 4;
            const char* sp = ht + drow * 512;
            uint4 a = *(const uint4*)(sp + (dcb ^ dsw));
            uint4 bq = *(const uint4*)(sp + ((dcb + 16) ^ dsw));
            char* dst = (char*)ybuf + (size_t)(bc * T_ + st + 1) * 8192 + tid * 32;
            *(uint4*)dst = a; *(uint4*)(dst + 16) = bq;
        }
    }
}

// out^T = Wd^T @ y^T per (16-batch, t) tile. One wave per (bc, 16 t-steps).
__global__ __launch_bounds__(64)
void proj_kernel(const _Float16* __restrict__ ybuf,
                 const float* __restrict__ Wd,   // [H,32]
                 const float* __restrict__ bd,   // [32]
                 float* __restrict__ out)        // [B,T,32]
{
    const int l  = threadIdx.x;
    const int lr = l & 15, lk = l >> 4;
    const int bc = blockIdx.x;
    const int tg = blockIdx.y;

    half8 wd[2][8];
#pragma unroll
    for (int c = 0; c < 2; ++c)
#pragma unroll
        for (int ks = 0; ks < 8; ++ks) {
            const float* src = Wd + (size_t)(ks*32 + lk*8) * 32 + c*16 + lr;
            half8 v;
#pragma unroll
            for (int j = 0; j < 8; ++j) v[j] = (_Float16)src[(size_t)j * 32];
            wd[c][ks] = v;
        }
    f32x4 bd0 = *(const f32x4*)(bd + lk*4);
    f32x4 bd1 = *(const f32x4*)(bd + 16 + lk*4);

    for (int t = tg*16; t < tg*16 + 16; ++t) {
        const _Float16* yt = ybuf + ((size_t)(bc*T_) + t) * 4096;
        f32x4 a0 = f32x4{0.f,0.f,0.f,0.f}, a1 = f32x4{0.f,0.f,0.f,0.f};
#pragma unroll
        for (int ks = 0; ks < 8; ++ks) {
            half8 b = *(const half8*)(yt + lr*256 + ks*32 + lk*8);
            a0 = mfma16(wd[0][ks], b, a0);
            a1 = mfma16(wd[1][ks], b, a1);
        }
        float* op = out + ((size_t)(bc*16 + lr) * T_ + t) * 32;
        *(f32x4*)(op + lk*4)      = a0 + bd0;
        *(f32x4*)(op + 16 + lk*4) = a1 + bd1;
    }
}

extern "C" void kernel_launch(void* const* d_in, const int* in_sizes, int n_in,
                              void* d_out, int out_size, void* d_ws, size_t ws_size,
                              hipStream_t stream) {
    const float* coeffs = (const float*)d_in[0];
    const float* times  = (const float*)d_in[1];
    const float* W_init = (const float*)d_in[2];
    const float* b_init = (const float*)d_in[3];
    const float* Wf     = (const float*)d_in[4];
    const float* bfv    = (const float*)d_in[5];
    const float* Wd     = (const float*)d_in[6];
    const float* bd     = (const float*)d_in[7];
    _Float16* wpack = (_Float16*)d_ws;                       // 512 KiB packed L2/L3 frags
    _Float16* ybuf  = (_Float16*)((char*)d_ws + 524288);     // 64 MiB
    float* out = (float*)d_out;

    hipLaunchKernelGGL(pack_kernel, dim3(64), dim3(256), 0, stream, Wf, wpack);

    const size_t lds_bytes = 131072 + 16384 + 4096 + 512;    // 152,064 B <= 160 KiB
    hipLaunchKernelGGL(ncde_kernel, dim3(64), dim3(256), lds_bytes, stream,
                       coeffs, times, W_init, b_init, Wf, bfv, wpack, ybuf);
    hipLaunchKernelGGL(proj_kernel, dim3(64, 8), dim3(64), 0, stream,
                       ybuf, Wd, bd, out);
}